// Round 1
// baseline (3553.891 us; speedup 1.0000x reference)
//
#include <hip/hip_runtime.h>

#define N_NODES 50000
#define N_EDGES 800000
#define N_LABEL 200000

// ---------------- degree / dinv ----------------
__global__ void k_deg_init(float* deg, int n) {
    int i = blockIdx.x * blockDim.x + threadIdx.x;
    if (i < n) deg[i] = 1.0f;  // self-loop
}

__global__ void k_deg_count(const int* __restrict__ dst, float* deg, int E) {
    int i = blockIdx.x * blockDim.x + threadIdx.x;
    if (i < E) atomicAdd(&deg[dst[i]], 1.0f);
}

__global__ void k_rsqrt(float* deg, int n) {
    int i = blockIdx.x * blockDim.x + threadIdx.x;
    if (i < n) deg[i] = rsqrtf(deg[i]);
}

// ---------------- GEMM + dinv scale ----------------
// in: [N][128] fp32, W: [128][M], writes A[r][c] = C[r][c] = (in@W)[r][c] * dinv[r]
// BM=64, BN=64, BK=K=128 (single K tile), 256 threads, 4x4 per thread.
__global__ __launch_bounds__(256)
void k_gemm_scale(const float* __restrict__ in, const float* __restrict__ W,
                  const float* __restrict__ dinv, float* __restrict__ A,
                  float* __restrict__ C, int N, int M) {
    const int LDA = 68;                  // padded leading dim (floats)
    __shared__ float As[128 * 68];       // [k][row]
    __shared__ float Bs[128 * 68];       // [k][col]
    int r0 = blockIdx.x * 64;
    int c0 = blockIdx.y * 64;
    int t = threadIdx.x;

    // load A tile (64 rows x 128 k), store transposed As[k][row]
#pragma unroll
    for (int i = 0; i < 8; ++i) {
        int idx = t + i * 256;           // 0..2047
        int row = idx >> 5;              // 0..63
        int kq  = (idx & 31) << 2;       // 0..124
        float4 v = make_float4(0.f, 0.f, 0.f, 0.f);
        int r = r0 + row;
        if (r < N) v = *(const float4*)&in[(long)r * 128 + kq];
        As[(kq + 0) * LDA + row] = v.x;
        As[(kq + 1) * LDA + row] = v.y;
        As[(kq + 2) * LDA + row] = v.z;
        As[(kq + 3) * LDA + row] = v.w;
    }
    // load B tile (128 k x 64 cols) into Bs[k][col]
#pragma unroll
    for (int i = 0; i < 8; ++i) {
        int idx = t + i * 256;
        int k  = idx >> 4;               // 0..127
        int cq = (idx & 15) << 2;        // 0..60
        float4 v = *(const float4*)&W[k * M + c0 + cq];
        *(float4*)&Bs[k * LDA + cq] = v;
    }
    __syncthreads();

    int ty = t >> 4, tx = t & 15;
    float acc[4][4] = {};
    const float* ap = &As[ty * 4];
    const float* bp = &Bs[tx * 4];
#pragma unroll 4
    for (int k = 0; k < 128; ++k) {
        float4 av = *(const float4*)&ap[k * LDA];
        float4 bv = *(const float4*)&bp[k * LDA];
        float a_[4] = {av.x, av.y, av.z, av.w};
        float b_[4] = {bv.x, bv.y, bv.z, bv.w};
#pragma unroll
        for (int i = 0; i < 4; ++i)
#pragma unroll
            for (int j = 0; j < 4; ++j)
                acc[i][j] += a_[i] * b_[j];
    }

#pragma unroll
    for (int i = 0; i < 4; ++i) {
        int r = r0 + ty * 4 + i;
        if (r < N) {
            float s = dinv[r];
            float4 v = make_float4(acc[i][0] * s, acc[i][1] * s,
                                   acc[i][2] * s, acc[i][3] * s);
            *(float4*)&A[(long)r * M + c0 + tx * 4] = v;
            *(float4*)&C[(long)r * M + c0 + tx * 4] = v;
        }
    }
}

// ---------------- edge scatter (atomic) ----------------
// C[dst] += A[src], M channels, float4 per thread, lg = log2(M/4)
__global__ void k_scatter(const int* __restrict__ srcv, const int* __restrict__ dstv,
                          const float* __restrict__ A, float* __restrict__ C,
                          int E, int M, int lg) {
    int t = blockIdx.x * blockDim.x + threadIdx.x;
    int e = t >> lg;
    if (e >= E) return;
    int q = (t & ((1 << lg) - 1)) << 2;
    int s = srcv[e], d = dstv[e];
    float4 v = *(const float4*)&A[(long)s * M + q];
    float* p = &C[(long)d * M + q];
    atomicAdd(p + 0, v.x);
    atomicAdd(p + 1, v.y);
    atomicAdd(p + 2, v.z);
    atomicAdd(p + 3, v.w);
}

// ---------------- finish: B = act(C*dinv + b) ----------------
__global__ void k_finish(const float* __restrict__ C, const float* __restrict__ dinv,
                         const float* __restrict__ bias, float* __restrict__ B,
                         int N, int M, int lg, int relu) {
    int t = blockIdx.x * blockDim.x + threadIdx.x;
    int node = t >> lg;
    if (node >= N) return;
    int q = (t & ((1 << lg) - 1)) << 2;
    float s = dinv[node];
    float4 v = *(const float4*)&C[(long)node * M + q];
    float4 bb = *(const float4*)&bias[q];
    v.x = v.x * s + bb.x;
    v.y = v.y * s + bb.y;
    v.z = v.z * s + bb.z;
    v.w = v.w * s + bb.w;
    if (relu) {
        v.x = fmaxf(v.x, 0.f); v.y = fmaxf(v.y, 0.f);
        v.z = fmaxf(v.z, 0.f); v.w = fmaxf(v.w, 0.f);
    }
    *(float4*)&B[(long)node * M + q] = v;
}

// ---------------- decode: out[i] = dot64(z[a], z[b]) ----------------
__global__ void k_decode(const float* __restrict__ z, const int* __restrict__ eli,
                         float* __restrict__ out, int L) {
    int t = blockIdx.x * blockDim.x + threadIdx.x;
    int e = t >> 4;
    int lane = t & 15;
    if (e >= L) return;
    int a = eli[e], b = eli[L + e];
    float4 va = *(const float4*)&z[(long)a * 64 + lane * 4];
    float4 vb = *(const float4*)&z[(long)b * 64 + lane * 4];
    float s = va.x * vb.x + va.y * vb.y + va.z * vb.z + va.w * vb.w;
    s += __shfl_xor(s, 1, 16);
    s += __shfl_xor(s, 2, 16);
    s += __shfl_xor(s, 4, 16);
    s += __shfl_xor(s, 8, 16);
    if (lane == 0) out[e] = s;
}

extern "C" void kernel_launch(void* const* d_in, const int* in_sizes, int n_in,
                              void* d_out, int out_size, void* d_ws, size_t ws_size,
                              hipStream_t stream) {
    const float* x   = (const float*)d_in[0];
    const float* W1  = (const float*)d_in[1];
    const float* b1  = (const float*)d_in[2];
    const float* W2  = (const float*)d_in[3];
    const float* b2  = (const float*)d_in[4];
    const float* W3  = (const float*)d_in[5];
    const float* b3  = (const float*)d_in[6];
    const int*   ei  = (const int*)d_in[7];
    const int*   eli = (const int*)d_in[8];
    float* out = (float*)d_out;

    float* ws   = (float*)d_ws;
    float* dinv = ws;                                    // N (padded to 50048)
    float* A    = dinv + 50048;                          // N*128  (hs, pre-scaled)
    float* C    = A + (long)N_NODES * 128;               // N*128  (aggregation)
    float* B    = C + (long)N_NODES * 128;               // N*128  (layer output z)

    const int* esrc = ei;
    const int* edst = ei + N_EDGES;

    // degree (with self-loops) -> dinv
    k_deg_init <<<(N_NODES + 255) / 256, 256, 0, stream>>>(dinv, N_NODES);
    k_deg_count<<<(N_EDGES + 255) / 256, 256, 0, stream>>>(edst, dinv, N_EDGES);
    k_rsqrt    <<<(N_NODES + 255) / 256, 256, 0, stream>>>(dinv, N_NODES);

    dim3 gemm_grid1((N_NODES + 63) / 64, 2);   // M=128
    dim3 gemm_grid3((N_NODES + 63) / 64, 1);   // M=64

    const int sc128 = (N_EDGES * 32 + 255) / 256;
    const int sc64  = (N_EDGES * 16 + 255) / 256;
    const int fi128 = (N_NODES * 32 + 255) / 256;
    const int fi64  = (N_NODES * 16 + 255) / 256;

    // layer 1: x -> B
    k_gemm_scale<<<gemm_grid1, 256, 0, stream>>>(x, W1, dinv, A, C, N_NODES, 128);
    k_scatter   <<<sc128, 256, 0, stream>>>(esrc, edst, A, C, N_EDGES, 128, 5);
    k_finish    <<<fi128, 256, 0, stream>>>(C, dinv, b1, B, N_NODES, 128, 5, 1);

    // layer 2: B -> B
    k_gemm_scale<<<gemm_grid1, 256, 0, stream>>>(B, W2, dinv, A, C, N_NODES, 128);
    k_scatter   <<<sc128, 256, 0, stream>>>(esrc, edst, A, C, N_EDGES, 128, 5);
    k_finish    <<<fi128, 256, 0, stream>>>(C, dinv, b2, B, N_NODES, 128, 5, 1);

    // layer 3: B -> B (M=64, no relu)
    k_gemm_scale<<<gemm_grid3, 256, 0, stream>>>(B, W3, dinv, A, C, N_NODES, 64);
    k_scatter   <<<sc64, 256, 0, stream>>>(esrc, edst, A, C, N_EDGES, 64, 4);
    k_finish    <<<fi64, 256, 0, stream>>>(C, dinv, b3, B, N_NODES, 64, 4, 0);

    // decode
    k_decode<<<(N_LABEL * 16 + 255) / 256, 256, 0, stream>>>(B, eli, out, N_LABEL);
}

// Round 2
// 394.326 us; speedup vs baseline: 9.0126x; 9.0126x over previous
//
#include <hip/hip_runtime.h>

#define N_NODES 50000
#define N_EDGES 800000
#define N_LABEL 200000

// ---------------- CSR build ----------------
__global__ void k_zero2(int* a, int* b, int n) {
    int i = blockIdx.x * blockDim.x + threadIdx.x;
    if (i < n) { a[i] = 0; b[i] = 0; }
}

__global__ void k_deg_count(const int* __restrict__ dst, int* cnt, int E) {
    int i = blockIdx.x * blockDim.x + threadIdx.x;
    if (i < E) atomicAdd(&cnt[dst[i]], 1);
}

// single-block inclusive scan: off[0]=0, off[i+1]=sum(cnt[0..i])
__global__ __launch_bounds__(1024)
void k_scan(const int* __restrict__ cnt, int* __restrict__ off, int n) {
    __shared__ int warp_sums[16];
    __shared__ int carry_s;
    int t = threadIdx.x;
    if (t == 0) carry_s = 0;
    __syncthreads();
    for (int base = 0; base < n; base += 1024) {
        int i = base + t;
        int v = (i < n) ? cnt[i] : 0;
        int lane = t & 63, w = t >> 6;
        int sv = v;
#pragma unroll
        for (int d = 1; d < 64; d <<= 1) {
            int u = __shfl_up(sv, d, 64);
            if (lane >= d) sv += u;
        }
        if (lane == 63) warp_sums[w] = sv;
        __syncthreads();
        if (t < 16) {
            int ws = warp_sums[t];
#pragma unroll
            for (int d = 1; d < 16; d <<= 1) {
                int u = __shfl_up(ws, d, 16);
                if (t >= d) ws += u;
            }
            warp_sums[t] = ws;
        }
        __syncthreads();
        int prev = (w > 0) ? warp_sums[w - 1] : 0;
        int incl = sv + prev + carry_s;
        if (i < n) off[i + 1] = incl;
        __syncthreads();
        if (t == 1023) carry_s = incl;
        __syncthreads();
    }
    if (t == 0) off[0] = 0;
}

__global__ void k_dinv(const int* __restrict__ cnt, float* dinv, int n) {
    int i = blockIdx.x * blockDim.x + threadIdx.x;
    if (i < n) dinv[i] = rsqrtf((float)cnt[i] + 1.0f);  // +1 self-loop
}

__global__ void k_bucket(const int* __restrict__ srcv, const int* __restrict__ dstv,
                         const int* __restrict__ off, int* cnt2, int* csr, int E) {
    int i = blockIdx.x * blockDim.x + threadIdx.x;
    if (i < E) {
        int d = dstv[i];
        int slot = off[d] + atomicAdd(&cnt2[d], 1);
        csr[slot] = srcv[i];
    }
}

// ---------------- GEMM + dinv scale ----------------
// A[r][c] = (in@W)[r][c] * dinv[r].  BM=64, BN=64, K=128, 256 thr, 4x4/thr.
__global__ __launch_bounds__(256)
void k_gemm_scale(const float* __restrict__ in, const float* __restrict__ W,
                  const float* __restrict__ dinv, float* __restrict__ A,
                  int N, int M) {
    const int LDA = 68;
    __shared__ float As[128 * 68];       // [k][row]
    __shared__ float Bs[128 * 68];       // [k][col]
    int r0 = blockIdx.x * 64;
    int c0 = blockIdx.y * 64;
    int t = threadIdx.x;

#pragma unroll
    for (int i = 0; i < 8; ++i) {
        int idx = t + i * 256;
        int row = idx >> 5;
        int kq  = (idx & 31) << 2;
        float4 v = make_float4(0.f, 0.f, 0.f, 0.f);
        int r = r0 + row;
        if (r < N) v = *(const float4*)&in[(long)r * 128 + kq];
        As[(kq + 0) * LDA + row] = v.x;
        As[(kq + 1) * LDA + row] = v.y;
        As[(kq + 2) * LDA + row] = v.z;
        As[(kq + 3) * LDA + row] = v.w;
    }
#pragma unroll
    for (int i = 0; i < 8; ++i) {
        int idx = t + i * 256;
        int k  = idx >> 4;
        int cq = (idx & 15) << 2;
        float4 v = *(const float4*)&W[k * M + c0 + cq];
        *(float4*)&Bs[k * LDA + cq] = v;
    }
    __syncthreads();

    int ty = t >> 4, tx = t & 15;
    float acc[4][4] = {};
    const float* ap = &As[ty * 4];
    const float* bp = &Bs[tx * 4];
#pragma unroll 4
    for (int k = 0; k < 128; ++k) {
        float4 av = *(const float4*)&ap[k * LDA];
        float4 bv = *(const float4*)&bp[k * LDA];
        float a_[4] = {av.x, av.y, av.z, av.w};
        float b_[4] = {bv.x, bv.y, bv.z, bv.w};
#pragma unroll
        for (int i = 0; i < 4; ++i)
#pragma unroll
            for (int j = 0; j < 4; ++j)
                acc[i][j] += a_[i] * b_[j];
    }

#pragma unroll
    for (int i = 0; i < 4; ++i) {
        int r = r0 + ty * 4 + i;
        if (r < N) {
            float s = dinv[r];
            *(float4*)&A[(long)r * M + c0 + tx * 4] =
                make_float4(acc[i][0] * s, acc[i][1] * s,
                            acc[i][2] * s, acc[i][3] * s);
        }
    }
}

// ---------------- fused gather + finish ----------------
// B[d] = act( dinv[d] * (A[d] + sum_{j in CSR[d]} A[csr[j]]) + bias )
// Mq = M/4 threads per node; lg = log2(Mq)
__global__ void k_gather(const float* __restrict__ A, const int* __restrict__ off,
                         const int* __restrict__ csr, const float* __restrict__ dinv,
                         const float* __restrict__ bias, float* __restrict__ B,
                         int N, int M, int lg, int relu) {
    int t = blockIdx.x * blockDim.x + threadIdx.x;
    int node = t >> lg;
    if (node >= N) return;
    int q = (t & ((1 << lg) - 1)) << 2;

    float4 acc = *(const float4*)&A[(long)node * M + q];  // self-loop
    int j = off[node], j1 = off[node + 1];
    for (; j + 4 <= j1; j += 4) {
        int s0 = csr[j], s1 = csr[j + 1], s2 = csr[j + 2], s3 = csr[j + 3];
        float4 v0 = *(const float4*)&A[(long)s0 * M + q];
        float4 v1 = *(const float4*)&A[(long)s1 * M + q];
        float4 v2 = *(const float4*)&A[(long)s2 * M + q];
        float4 v3 = *(const float4*)&A[(long)s3 * M + q];
        acc.x += v0.x + v1.x + v2.x + v3.x;
        acc.y += v0.y + v1.y + v2.y + v3.y;
        acc.z += v0.z + v1.z + v2.z + v3.z;
        acc.w += v0.w + v1.w + v2.w + v3.w;
    }
    for (; j < j1; ++j) {
        int s = csr[j];
        float4 v = *(const float4*)&A[(long)s * M + q];
        acc.x += v.x; acc.y += v.y; acc.z += v.z; acc.w += v.w;
    }
    float sc = dinv[node];
    float4 bb = *(const float4*)&bias[q];
    acc.x = acc.x * sc + bb.x;
    acc.y = acc.y * sc + bb.y;
    acc.z = acc.z * sc + bb.z;
    acc.w = acc.w * sc + bb.w;
    if (relu) {
        acc.x = fmaxf(acc.x, 0.f); acc.y = fmaxf(acc.y, 0.f);
        acc.z = fmaxf(acc.z, 0.f); acc.w = fmaxf(acc.w, 0.f);
    }
    *(float4*)&B[(long)node * M + q] = acc;
}

// ---------------- decode: out[i] = dot64(z[a], z[b]) ----------------
__global__ void k_decode(const float* __restrict__ z, const int* __restrict__ eli,
                         float* __restrict__ out, int L) {
    int t = blockIdx.x * blockDim.x + threadIdx.x;
    int e = t >> 4;
    int lane = t & 15;
    if (e >= L) return;
    int a = eli[e], b = eli[L + e];
    float4 va = *(const float4*)&z[(long)a * 64 + lane * 4];
    float4 vb = *(const float4*)&z[(long)b * 64 + lane * 4];
    float s = va.x * vb.x + va.y * vb.y + va.z * vb.z + va.w * vb.w;
    s += __shfl_xor(s, 1, 16);
    s += __shfl_xor(s, 2, 16);
    s += __shfl_xor(s, 4, 16);
    s += __shfl_xor(s, 8, 16);
    if (lane == 0) out[e] = s;
}

extern "C" void kernel_launch(void* const* d_in, const int* in_sizes, int n_in,
                              void* d_out, int out_size, void* d_ws, size_t ws_size,
                              hipStream_t stream) {
    const float* x   = (const float*)d_in[0];
    const float* W1  = (const float*)d_in[1];
    const float* b1  = (const float*)d_in[2];
    const float* W2  = (const float*)d_in[3];
    const float* b2  = (const float*)d_in[4];
    const float* W3  = (const float*)d_in[5];
    const float* b3  = (const float*)d_in[6];
    const int*   ei  = (const int*)d_in[7];
    const int*   eli = (const int*)d_in[8];
    float* out = (float*)d_out;

    char* ws = (char*)d_ws;
    float* dinv = (float*)ws;                 ws += 50048 * 4;
    float* A    = (float*)ws;                 ws += (long)N_NODES * 128 * 4;
    float* B    = (float*)ws;                 ws += (long)N_NODES * 128 * 4;
    int*   cnt  = (int*)ws;                   ws += 50048 * 4;
    int*   cnt2 = (int*)ws;                   ws += 50048 * 4;
    int*   off  = (int*)ws;                   ws += 50048 * 4;
    int*   csr  = (int*)ws;                   ws += (long)N_EDGES * 4;

    const int* esrc = ei;
    const int* edst = ei + N_EDGES;

    // CSR build + dinv
    k_zero2    <<<(N_NODES + 255) / 256, 256, 0, stream>>>(cnt, cnt2, N_NODES);
    k_deg_count<<<(N_EDGES + 255) / 256, 256, 0, stream>>>(edst, cnt, N_EDGES);
    k_scan     <<<1, 1024, 0, stream>>>(cnt, off, N_NODES);
    k_dinv     <<<(N_NODES + 255) / 256, 256, 0, stream>>>(cnt, dinv, N_NODES);
    k_bucket   <<<(N_EDGES + 255) / 256, 256, 0, stream>>>(esrc, edst, off, cnt2, csr, N_EDGES);

    dim3 gemm_grid1((N_NODES + 63) / 64, 2);   // M=128
    dim3 gemm_grid3((N_NODES + 63) / 64, 1);   // M=64

    const int ga128 = (N_NODES * 32 + 255) / 256;
    const int ga64  = (N_NODES * 16 + 255) / 256;

    // layer 1: x -> B
    k_gemm_scale<<<gemm_grid1, 256, 0, stream>>>(x, W1, dinv, A, N_NODES, 128);
    k_gather    <<<ga128, 256, 0, stream>>>(A, off, csr, dinv, b1, B, N_NODES, 128, 5, 1);

    // layer 2: B -> B
    k_gemm_scale<<<gemm_grid1, 256, 0, stream>>>(B, W2, dinv, A, N_NODES, 128);
    k_gather    <<<ga128, 256, 0, stream>>>(A, off, csr, dinv, b2, B, N_NODES, 128, 5, 1);

    // layer 3: B -> B (M=64, no relu)
    k_gemm_scale<<<gemm_grid3, 256, 0, stream>>>(B, W3, dinv, A, N_NODES, 64);
    k_gather    <<<ga64, 256, 0, stream>>>(A, off, csr, dinv, b3, B, N_NODES, 64, 4, 0);

    // decode
    k_decode<<<(N_LABEL * 16 + 255) / 256, 256, 0, stream>>>(B, eli, out, N_LABEL);
}

// Round 3
// 352.553 us; speedup vs baseline: 10.0804x; 1.1185x over previous
//
#include <hip/hip_runtime.h>

#define N_NODES 50000
#define N_EDGES 800000
#define N_LABEL 200000

// ---------------- CSR build ----------------
__global__ void k_zero2(int* a, int* b, int n) {
    int i = blockIdx.x * blockDim.x + threadIdx.x;
    if (i < n) { a[i] = 0; b[i] = 0; }
}

__global__ void k_deg_count(const int* __restrict__ dst, int* cnt, int E) {
    int i = blockIdx.x * blockDim.x + threadIdx.x;
    if (i < E) atomicAdd(&cnt[dst[i]], 1);
}

// per-block sum of cnt + dinv computation
__global__ __launch_bounds__(256)
void k_partial(const int* __restrict__ cnt, float* __restrict__ dinv,
               int* __restrict__ bsum, int N) {
    __shared__ int wsum[4];
    int b = blockIdx.x, t = threadIdx.x;
    int i = b * 256 + t;
    int v = (i < N) ? cnt[i] : 0;
    if (i < N) dinv[i] = rsqrtf((float)v + 1.0f);  // +1 self-loop
    int s = v;
#pragma unroll
    for (int d = 1; d < 64; d <<= 1) s += __shfl_xor(s, d, 64);
    if ((t & 63) == 0) wsum[t >> 6] = s;
    __syncthreads();
    if (t == 0) bsum[b] = wsum[0] + wsum[1] + wsum[2] + wsum[3];
}

// single block: exclusive scan of block sums (NB <= 256)
__global__ __launch_bounds__(256)
void k_scan_bsum(const int* __restrict__ bsum, int* __restrict__ boff, int NB) {
    __shared__ int wsum[4];
    int t = threadIdx.x;
    int v = (t < NB) ? bsum[t] : 0;
    int lane = t & 63, w = t >> 6;
    int sv = v;
#pragma unroll
    for (int d = 1; d < 64; d <<= 1) {
        int u = __shfl_up(sv, d, 64);
        if (lane >= d) sv += u;
    }
    if (lane == 63) wsum[w] = sv;
    __syncthreads();
    int add = 0;
    for (int ww = 0; ww < w; ++ww) add += wsum[ww];
    if (t < NB) boff[t] = sv + add - v;  // exclusive
}

// off[i+1] = boff[block] + inclusive_local_scan(cnt)[i]; off[0] = 0
__global__ __launch_bounds__(256)
void k_offsets(const int* __restrict__ cnt, const int* __restrict__ boff,
               int* __restrict__ off, int N) {
    __shared__ int wsum[4];
    int b = blockIdx.x, t = threadIdx.x;
    int i = b * 256 + t;
    int v = (i < N) ? cnt[i] : 0;
    int lane = t & 63, w = t >> 6;
    int sv = v;
#pragma unroll
    for (int d = 1; d < 64; d <<= 1) {
        int u = __shfl_up(sv, d, 64);
        if (lane >= d) sv += u;
    }
    if (lane == 63) wsum[w] = sv;
    __syncthreads();
    int add = boff[b];
    for (int ww = 0; ww < w; ++ww) add += wsum[ww];
    if (i < N) off[i + 1] = add + sv;
    if (i == 0) off[0] = 0;
}

__global__ void k_bucket(const int* __restrict__ srcv, const int* __restrict__ dstv,
                         const int* __restrict__ off, int* cnt2, int* csr, int E) {
    int i = blockIdx.x * blockDim.x + threadIdx.x;
    if (i < E) {
        int d = dstv[i];
        int slot = off[d] + atomicAdd(&cnt2[d], 1);
        csr[slot] = srcv[i];
    }
}

// ---------------- GEMM + dinv scale ----------------
// A[r][c] = (in@W)[r][c] * dinv[r].  BM=64, BN=64, K=128, 256 thr, 4x4/thr.
__global__ __launch_bounds__(256)
void k_gemm_scale(const float* __restrict__ in, const float* __restrict__ W,
                  const float* __restrict__ dinv, float* __restrict__ A,
                  int N, int M) {
    const int LDA = 68;
    __shared__ float As[128 * 68];       // [k][row]
    __shared__ float Bs[128 * 68];       // [k][col]
    int r0 = blockIdx.x * 64;
    int c0 = blockIdx.y * 64;
    int t = threadIdx.x;

#pragma unroll
    for (int i = 0; i < 8; ++i) {
        int idx = t + i * 256;
        int row = idx >> 5;
        int kq  = (idx & 31) << 2;
        float4 v = make_float4(0.f, 0.f, 0.f, 0.f);
        int r = r0 + row;
        if (r < N) v = *(const float4*)&in[(long)r * 128 + kq];
        As[(kq + 0) * LDA + row] = v.x;
        As[(kq + 1) * LDA + row] = v.y;
        As[(kq + 2) * LDA + row] = v.z;
        As[(kq + 3) * LDA + row] = v.w;
    }
#pragma unroll
    for (int i = 0; i < 8; ++i) {
        int idx = t + i * 256;
        int k  = idx >> 4;
        int cq = (idx & 15) << 2;
        float4 v = *(const float4*)&W[k * M + c0 + cq];
        *(float4*)&Bs[k * LDA + cq] = v;
    }
    __syncthreads();

    int ty = t >> 4, tx = t & 15;
    float acc[4][4] = {};
    const float* ap = &As[ty * 4];
    const float* bp = &Bs[tx * 4];
#pragma unroll 4
    for (int k = 0; k < 128; ++k) {
        float4 av = *(const float4*)&ap[k * LDA];
        float4 bv = *(const float4*)&bp[k * LDA];
        float a_[4] = {av.x, av.y, av.z, av.w};
        float b_[4] = {bv.x, bv.y, bv.z, bv.w};
#pragma unroll
        for (int i = 0; i < 4; ++i)
#pragma unroll
            for (int j = 0; j < 4; ++j)
                acc[i][j] += a_[i] * b_[j];
    }

#pragma unroll
    for (int i = 0; i < 4; ++i) {
        int r = r0 + ty * 4 + i;
        if (r < N) {
            float s = dinv[r];
            *(float4*)&A[(long)r * M + c0 + tx * 4] =
                make_float4(acc[i][0] * s, acc[i][1] * s,
                            acc[i][2] * s, acc[i][3] * s);
        }
    }
}

// ---------------- fused gather + finish ----------------
// B[d] = act( dinv[d] * (A[d] + sum_{j in CSR[d]} A[csr[j]]) + bias )
__global__ void k_gather(const float* __restrict__ A, const int* __restrict__ off,
                         const int* __restrict__ csr, const float* __restrict__ dinv,
                         const float* __restrict__ bias, float* __restrict__ B,
                         int N, int M, int lg, int relu) {
    int t = blockIdx.x * blockDim.x + threadIdx.x;
    int node = t >> lg;
    if (node >= N) return;
    int q = (t & ((1 << lg) - 1)) << 2;
    const float* Aq = A + q;

    float4 acc = *(const float4*)&Aq[(long)node * M];  // self-loop
    float4 acc1 = make_float4(0.f, 0.f, 0.f, 0.f);
    int j = off[node], j1 = off[node + 1];
    for (; j + 8 <= j1; j += 8) {
        int s0 = csr[j + 0], s1 = csr[j + 1], s2 = csr[j + 2], s3 = csr[j + 3];
        int s4 = csr[j + 4], s5 = csr[j + 5], s6 = csr[j + 6], s7 = csr[j + 7];
        float4 v0 = *(const float4*)&Aq[(long)s0 * M];
        float4 v1 = *(const float4*)&Aq[(long)s1 * M];
        float4 v2 = *(const float4*)&Aq[(long)s2 * M];
        float4 v3 = *(const float4*)&Aq[(long)s3 * M];
        float4 v4 = *(const float4*)&Aq[(long)s4 * M];
        float4 v5 = *(const float4*)&Aq[(long)s5 * M];
        float4 v6 = *(const float4*)&Aq[(long)s6 * M];
        float4 v7 = *(const float4*)&Aq[(long)s7 * M];
        acc.x += v0.x + v1.x + v2.x + v3.x;
        acc.y += v0.y + v1.y + v2.y + v3.y;
        acc.z += v0.z + v1.z + v2.z + v3.z;
        acc.w += v0.w + v1.w + v2.w + v3.w;
        acc1.x += v4.x + v5.x + v6.x + v7.x;
        acc1.y += v4.y + v5.y + v6.y + v7.y;
        acc1.z += v4.z + v5.z + v6.z + v7.z;
        acc1.w += v4.w + v5.w + v6.w + v7.w;
    }
    for (; j + 2 <= j1; j += 2) {
        int s0 = csr[j + 0], s1 = csr[j + 1];
        float4 v0 = *(const float4*)&Aq[(long)s0 * M];
        float4 v1 = *(const float4*)&Aq[(long)s1 * M];
        acc.x += v0.x + v1.x; acc.y += v0.y + v1.y;
        acc.z += v0.z + v1.z; acc.w += v0.w + v1.w;
    }
    if (j < j1) {
        int s = csr[j];
        float4 v = *(const float4*)&Aq[(long)s * M];
        acc.x += v.x; acc.y += v.y; acc.z += v.z; acc.w += v.w;
    }
    acc.x += acc1.x; acc.y += acc1.y; acc.z += acc1.z; acc.w += acc1.w;

    float sc = dinv[node];
    float4 bb = *(const float4*)&bias[q];
    acc.x = acc.x * sc + bb.x;
    acc.y = acc.y * sc + bb.y;
    acc.z = acc.z * sc + bb.z;
    acc.w = acc.w * sc + bb.w;
    if (relu) {
        acc.x = fmaxf(acc.x, 0.f); acc.y = fmaxf(acc.y, 0.f);
        acc.z = fmaxf(acc.z, 0.f); acc.w = fmaxf(acc.w, 0.f);
    }
    *(float4*)&B[(long)node * M + q] = acc;
}

// ---------------- decode: out[i] = dot64(z[a], z[b]) ----------------
__global__ void k_decode(const float* __restrict__ z, const int* __restrict__ eli,
                         float* __restrict__ out, int L) {
    int t = blockIdx.x * blockDim.x + threadIdx.x;
    int e = t >> 4;
    int lane = t & 15;
    if (e >= L) return;
    int a = eli[e], b = eli[L + e];
    float4 va = *(const float4*)&z[(long)a * 64 + lane * 4];
    float4 vb = *(const float4*)&z[(long)b * 64 + lane * 4];
    float s = va.x * vb.x + va.y * vb.y + va.z * vb.z + va.w * vb.w;
    s += __shfl_xor(s, 1, 16);
    s += __shfl_xor(s, 2, 16);
    s += __shfl_xor(s, 4, 16);
    s += __shfl_xor(s, 8, 16);
    if (lane == 0) out[e] = s;
}

extern "C" void kernel_launch(void* const* d_in, const int* in_sizes, int n_in,
                              void* d_out, int out_size, void* d_ws, size_t ws_size,
                              hipStream_t stream) {
    const float* x   = (const float*)d_in[0];
    const float* W1  = (const float*)d_in[1];
    const float* b1  = (const float*)d_in[2];
    const float* W2  = (const float*)d_in[3];
    const float* b2  = (const float*)d_in[4];
    const float* W3  = (const float*)d_in[5];
    const float* b3  = (const float*)d_in[6];
    const int*   ei  = (const int*)d_in[7];
    const int*   eli = (const int*)d_in[8];
    float* out = (float*)d_out;

    char* ws = (char*)d_ws;
    float* dinv = (float*)ws;                 ws += 50048 * 4;
    float* A    = (float*)ws;                 ws += (long)N_NODES * 128 * 4;
    float* B    = (float*)ws;                 ws += (long)N_NODES * 128 * 4;
    int*   cnt  = (int*)ws;                   ws += 50048 * 4;
    int*   cnt2 = (int*)ws;                   ws += 50048 * 4;
    int*   off  = (int*)ws;                   ws += 50048 * 4;
    int*   csr  = (int*)ws;                   ws += (long)N_EDGES * 4;
    int*   bsum = (int*)ws;                   ws += 256 * 4;
    int*   boff = (int*)ws;                   ws += 256 * 4;

    const int* esrc = ei;
    const int* edst = ei + N_EDGES;

    const int NB = (N_NODES + 255) / 256;  // 196 blocks

    // CSR build + dinv (parallel scan)
    k_zero2    <<<NB, 256, 0, stream>>>(cnt, cnt2, N_NODES);
    k_deg_count<<<(N_EDGES + 255) / 256, 256, 0, stream>>>(edst, cnt, N_EDGES);
    k_partial  <<<NB, 256, 0, stream>>>(cnt, dinv, bsum, N_NODES);
    k_scan_bsum<<<1, 256, 0, stream>>>(bsum, boff, NB);
    k_offsets  <<<NB, 256, 0, stream>>>(cnt, boff, off, N_NODES);
    k_bucket   <<<(N_EDGES + 255) / 256, 256, 0, stream>>>(esrc, edst, off, cnt2, csr, N_EDGES);

    dim3 gemm_grid1((N_NODES + 63) / 64, 2);   // M=128
    dim3 gemm_grid3((N_NODES + 63) / 64, 1);   // M=64

    const int ga128 = (N_NODES * 32 + 255) / 256;
    const int ga64  = (N_NODES * 16 + 255) / 256;

    // layer 1: x -> B
    k_gemm_scale<<<gemm_grid1, 256, 0, stream>>>(x, W1, dinv, A, N_NODES, 128);
    k_gather    <<<ga128, 256, 0, stream>>>(A, off, csr, dinv, b1, B, N_NODES, 128, 5, 1);

    // layer 2: B -> B
    k_gemm_scale<<<gemm_grid1, 256, 0, stream>>>(B, W2, dinv, A, N_NODES, 128);
    k_gather    <<<ga128, 256, 0, stream>>>(A, off, csr, dinv, b2, B, N_NODES, 128, 5, 1);

    // layer 3: B -> B (M=64, no relu)
    k_gemm_scale<<<gemm_grid3, 256, 0, stream>>>(B, W3, dinv, A, N_NODES, 64);
    k_gather    <<<ga64, 256, 0, stream>>>(A, off, csr, dinv, b3, B, N_NODES, 64, 4, 0);

    // decode
    k_decode<<<(N_LABEL * 16 + 255) / 256, 256, 0, stream>>>(B, eli, out, N_LABEL);
}